// Round 1
// baseline (353.902 us; speedup 1.0000x reference)
//
#include <hip/hip_runtime.h>
#include <hip/hip_bf16.h>
#include <stdint.h>

typedef unsigned short u16;
typedef __attribute__((ext_vector_type(8))) short bf16x8;
typedef __attribute__((ext_vector_type(4))) float f32x4;

__device__ __forceinline__ u16 f2bf(float f) {
  union { float f; unsigned u; } v; v.f = f;
  unsigned r = v.u + 0x7fffu + ((v.u >> 16) & 1u);
  return (u16)(r >> 16);
}
__device__ __forceinline__ float bf2f(u16 h) {
  union { unsigned u; float f; } v; v.u = ((unsigned)h) << 16;
  return v.f;
}

// ---------------- fp32 -> bf16 conversion: x (4096x1024) + 4 weights (1024x1024)
__global__ void convert_kernel(const float4* __restrict__ x, const float4* __restrict__ wq,
                               const float4* __restrict__ wk, const float4* __restrict__ wv,
                               const float4* __restrict__ wp,
                               u16* __restrict__ xb, u16* __restrict__ wqb, u16* __restrict__ wkb,
                               u16* __restrict__ wvb, u16* __restrict__ wpb) {
  int i = blockIdx.x * 256 + threadIdx.x;   // 0 .. 2097151 (float4 units)
  const int NX = 1048576, NW = 262144;
  const float4* src; u16* dst; int off;
  if (i < NX)            { src = x;  dst = xb;  off = i; }
  else if (i < NX + NW)  { src = wq; dst = wqb; off = i - NX; }
  else if (i < NX + 2*NW){ src = wk; dst = wkb; off = i - NX - NW; }
  else if (i < NX + 3*NW){ src = wv; dst = wvb; off = i - NX - 2*NW; }
  else                   { src = wp; dst = wpb; off = i - NX - 3*NW; }
  float4 v = src[off];
  ushort4 ov = make_ushort4(f2bf(v.x), f2bf(v.y), f2bf(v.z), f2bf(v.w));
  *(ushort4*)&dst[off * 4] = ov;
}

// ---------------- NT GEMM: C[M,N] = A[M,K] * B[N,K]^T + bias, K=N=1024
// 128x128 tile, BK=32, 4 waves (2x2), mfma_f32_16x16x32_bf16
template<int OUT_BF16>
__global__ __launch_bounds__(256) void gemm_bt_kernel(
    const u16* __restrict__ A,
    const u16* __restrict__ B0, const u16* __restrict__ B1, const u16* __restrict__ B2,
    const float* __restrict__ bias0, const float* __restrict__ bias1, const float* __restrict__ bias2,
    void* out0, void* out1, void* out2)
{
  __shared__ __align__(16) u16 As[128 * 40];   // +8 pad: row stride 80B = 20 banks
  __shared__ __align__(16) u16 Bs[128 * 40];
  const int z = blockIdx.z;
  const u16* Bw = (z == 0) ? B0 : (z == 1) ? B1 : B2;
  const float* bias = (z == 0) ? bias0 : (z == 1) ? bias1 : bias2;
  void* outv = (z == 0) ? out0 : (z == 1) ? out1 : out2;
  const int tid = threadIdx.x;
  const int lane = tid & 63, w = tid >> 6;
  const int wr = w >> 1, wc = w & 1;
  const int quad = lane >> 4, l15 = lane & 15;
  const int m0 = blockIdx.y * 128, n0 = blockIdx.x * 128;

  f32x4 acc[4][4] = {};
  for (int k0 = 0; k0 < 1024; k0 += 32) {
    __syncthreads();
    #pragma unroll
    for (int c = tid; c < 512; c += 256) {
      const int row = c >> 2, kc = c & 3;
      float4 av = *(const float4*)&A[(m0 + row) * 1024 + k0 + kc * 8];
      float4 bv = *(const float4*)&Bw[(n0 + row) * 1024 + k0 + kc * 8];
      *(float4*)&As[row * 40 + kc * 8] = av;
      *(float4*)&Bs[row * 40 + kc * 8] = bv;
    }
    __syncthreads();
    bf16x8 af[4], bfr[4];
    #pragma unroll
    for (int mt = 0; mt < 4; mt++)
      af[mt] = *(const bf16x8*)&As[(wr * 64 + mt * 16 + l15) * 40 + quad * 8];
    #pragma unroll
    for (int nt = 0; nt < 4; nt++)
      bfr[nt] = *(const bf16x8*)&Bs[(wc * 64 + nt * 16 + l15) * 40 + quad * 8];
    #pragma unroll
    for (int mt = 0; mt < 4; mt++)
      #pragma unroll
      for (int nt = 0; nt < 4; nt++)
        acc[mt][nt] = __builtin_amdgcn_mfma_f32_16x16x32_bf16(af[mt], bfr[nt], acc[mt][nt], 0, 0, 0);
  }
  #pragma unroll
  for (int mt = 0; mt < 4; mt++)
    #pragma unroll
    for (int nt = 0; nt < 4; nt++)
      #pragma unroll
      for (int r = 0; r < 4; r++) {
        const int row = m0 + wr * 64 + mt * 16 + quad * 4 + r;
        const int col = n0 + wc * 64 + nt * 16 + l15;
        float v = acc[mt][nt][r] + bias[col];
        if (OUT_BF16) ((u16*)outv)[row * 1024 + col] = f2bf(v);
        else          ((float*)outv)[row * 1024 + col] = v;
      }
}

// ---------------- RoPE in-place on q and k (bf16), layout [B*T][H*64]
__global__ void rope_kernel(u16* __restrict__ qb, u16* __restrict__ kb) {
  int i = blockIdx.x * 256 + threadIdx.x;   // 0 .. 4194303
  const int HALF = 2097152;                 // 4096 rows * 16 heads * 32 pairs
  u16* p = (i < HALF) ? qb : kb;
  int j = (i < HALF) ? i : i - HALF;
  int d = j & 31;
  int hh = (j >> 5) & 15;
  int row = j >> 9;                         // b*T + t, 0..4095
  int t = row & 2047;
  float inv = expf(-0.28782313662425572f * (float)d);  // ln(10000)/32
  float ang = (float)t * inv;
  float cs = cosf(ang), sn = sinf(ang);
  int base = row * 1024 + hh * 64 + d;
  float a0 = bf2f(p[base]), a1 = bf2f(p[base + 32]);
  p[base]      = f2bf(a0 * cs - a1 * sn);
  p[base + 32] = f2bf(a1 * cs + a0 * sn);
}

// ---------------- causal flash attention, block = (64 q-rows, head, batch)
__global__ __launch_bounds__(256) void attn_kernel(
    const u16* __restrict__ qb, const u16* __restrict__ kb,
    const u16* __restrict__ vb, u16* __restrict__ yb)
{
  __shared__ __align__(16) u16 K_lds[64 * 72];      // [s][d], pad to 72
  __shared__ __align__(16) u16 V_lds[64 * 72];      // transposed: [d][s]
  __shared__ __align__(16) u16 P_lds[4][16 * 72];   // per-wave P tile
  const int qt = blockIdx.x, hh = blockIdx.y, b = blockIdx.z;
  const int tid = threadIdx.x, lane = tid & 63, w = tid >> 6;
  const int quad = lane >> 4, l15 = lane & 15;
  const int bh = b * (2048 * 1024) + hh * 64;
  const int qrow = qt * 64 + w * 16 + l15;
  bf16x8 qf0 = *(const bf16x8*)&qb[bh + qrow * 1024 + quad * 8];
  bf16x8 qf1 = *(const bf16x8*)&qb[bh + qrow * 1024 + 32 + quad * 8];
  f32x4 o_acc[4] = {};
  float m_i[4], l_i[4];
  #pragma unroll
  for (int r = 0; r < 4; r++) { m_i[r] = -1e30f; l_i[r] = 0.0f; }

  for (int j = 0; j <= qt; j++) {
    __syncthreads();
    const int s0 = j * 64;
    #pragma unroll
    for (int c = tid; c < 512; c += 256) {
      const int row = c >> 3, cc = c & 7;
      const int gidx = bh + (s0 + row) * 1024 + cc * 8;
      float4 kvv = *(const float4*)&kb[gidx];
      *(float4*)&K_lds[row * 72 + cc * 8] = kvv;
      float4 vvv = *(const float4*)&vb[gidx];
      union { float4 f; u16 u[8]; } vu; vu.f = vvv;
      #pragma unroll
      for (int k2 = 0; k2 < 8; k2++) {       // permuted to spread LDS banks
        const int kk = (k2 + cc) & 7;
        V_lds[(cc * 8 + kk) * 72 + row] = vu.u[kk];
      }
    }
    __syncthreads();

    // S = Q K^T for this 64x64 tile (per wave: 16 rows)
    f32x4 s_acc[4];
    #pragma unroll
    for (int nt = 0; nt < 4; nt++) {
      bf16x8 kf0 = *(const bf16x8*)&K_lds[(nt * 16 + l15) * 72 + quad * 8];
      bf16x8 kf1 = *(const bf16x8*)&K_lds[(nt * 16 + l15) * 72 + 32 + quad * 8];
      f32x4 zz = {};
      zz = __builtin_amdgcn_mfma_f32_16x16x32_bf16(qf0, kf0, zz, 0, 0, 0);
      zz = __builtin_amdgcn_mfma_f32_16x16x32_bf16(qf1, kf1, zz, 0, 0, 0);
      s_acc[nt] = zz;
    }
    const float scale = 0.125f;   // 1/sqrt(64)
    const int trow = w * 16 + quad * 4;
    if (j == qt) {
      #pragma unroll
      for (int nt = 0; nt < 4; nt++)
        #pragma unroll
        for (int r = 0; r < 4; r++) {
          float sv = s_acc[nt][r] * scale;
          if (nt * 16 + l15 > trow + r) sv = -1e30f;   // causal mask (diag tile only)
          s_acc[nt][r] = sv;
        }
    } else {
      #pragma unroll
      for (int nt = 0; nt < 4; nt++)
        #pragma unroll
        for (int r = 0; r < 4; r++) s_acc[nt][r] *= scale;
    }
    // online softmax; row = quad*4+r, replicated across the quad's 16 lanes
    float mx[4];
    #pragma unroll
    for (int r = 0; r < 4; r++)
      mx[r] = fmaxf(fmaxf(s_acc[0][r], s_acc[1][r]), fmaxf(s_acc[2][r], s_acc[3][r]));
    #pragma unroll
    for (int off = 8; off >= 1; off >>= 1)
      #pragma unroll
      for (int r = 0; r < 4; r++) mx[r] = fmaxf(mx[r], __shfl_xor(mx[r], off));
    float al[4];
    #pragma unroll
    for (int r = 0; r < 4; r++) {
      float mn = fmaxf(m_i[r], mx[r]);
      al[r] = __expf(m_i[r] - mn);
      m_i[r] = mn;
    }
    float rs[4] = {0.f, 0.f, 0.f, 0.f};
    #pragma unroll
    for (int nt = 0; nt < 4; nt++)
      #pragma unroll
      for (int r = 0; r < 4; r++) {
        float pv = __expf(s_acc[nt][r] - m_i[r]);
        rs[r] += pv;
        P_lds[w][(quad * 4 + r) * 72 + nt * 16 + l15] = f2bf(pv);
      }
    #pragma unroll
    for (int off = 8; off >= 1; off >>= 1)
      #pragma unroll
      for (int r = 0; r < 4; r++) rs[r] += __shfl_xor(rs[r], off);
    #pragma unroll
    for (int r = 0; r < 4; r++) l_i[r] = l_i[r] * al[r] + rs[r];
    #pragma unroll
    for (int dt = 0; dt < 4; dt++)
      #pragma unroll
      for (int r = 0; r < 4; r++) o_acc[dt][r] *= al[r];
    // O += P V   (P via LDS round-trip: C-layout -> A-layout)
    #pragma unroll
    for (int ss = 0; ss < 2; ss++) {
      bf16x8 pf = *(const bf16x8*)&P_lds[w][l15 * 72 + ss * 32 + quad * 8];
      #pragma unroll
      for (int dt = 0; dt < 4; dt++) {
        bf16x8 vf = *(const bf16x8*)&V_lds[(dt * 16 + l15) * 72 + ss * 32 + quad * 8];
        o_acc[dt] = __builtin_amdgcn_mfma_f32_16x16x32_bf16(pf, vf, o_acc[dt], 0, 0, 0);
      }
    }
  }
  #pragma unroll
  for (int dt = 0; dt < 4; dt++)
    #pragma unroll
    for (int r = 0; r < 4; r++) {
      float ov = o_acc[dt][r] / l_i[r];
      yb[bh + (qt * 64 + w * 16 + quad * 4 + r) * 1024 + dt * 16 + l15] = f2bf(ov);
    }
}

extern "C" void kernel_launch(void* const* d_in, const int* in_sizes, int n_in,
                              void* d_out, int out_size, void* d_ws, size_t ws_size,
                              hipStream_t stream) {
  const float* x  = (const float*)d_in[0];
  const float* Wq = (const float*)d_in[1];
  const float* bq = (const float*)d_in[2];
  const float* Wk = (const float*)d_in[3];
  const float* bk = (const float*)d_in[4];
  const float* Wv = (const float*)d_in[5];
  const float* bv = (const float*)d_in[6];
  const float* Wp = (const float*)d_in[7];
  const float* bp = (const float*)d_in[8];

  char* ws = (char*)d_ws;
  u16* xb  = (u16*)(ws);                          // 8 MB (reused as yb after attention)
  u16* wqb = (u16*)(ws + (8u  << 20));            // 2 MB
  u16* wkb = (u16*)(ws + (10u << 20));
  u16* wvb = (u16*)(ws + (12u << 20));
  u16* wpb = (u16*)(ws + (14u << 20));
  u16* qb  = (u16*)(ws + (16u << 20));            // 8 MB
  u16* kb  = (u16*)(ws + (24u << 20));            // 8 MB
  u16* vb  = (u16*)(ws + (32u << 20));            // 8 MB  (total 40 MB)
  u16* yb  = xb;

  convert_kernel<<<8192, 256, 0, stream>>>((const float4*)x, (const float4*)Wq, (const float4*)Wk,
                                           (const float4*)Wv, (const float4*)Wp,
                                           xb, wqb, wkb, wvb, wpb);
  gemm_bt_kernel<1><<<dim3(8, 32, 3), 256, 0, stream>>>(xb, wqb, wkb, wvb, bq, bk, bv,
                                                        (void*)qb, (void*)kb, (void*)vb);
  rope_kernel<<<16384, 256, 0, stream>>>(qb, kb);
  attn_kernel<<<dim3(32, 16, 2), 256, 0, stream>>>(qb, kb, vb, yb);
  gemm_bt_kernel<0><<<dim3(8, 32, 1), 256, 0, stream>>>(yb, wpb, wpb, wpb, bp, bp, bp,
                                                        (void*)d_out, (void*)d_out, (void*)d_out);
}

// Round 2
// 274.252 us; speedup vs baseline: 1.2904x; 1.2904x over previous
//
#include <hip/hip_runtime.h>
#include <hip/hip_bf16.h>
#include <stdint.h>

typedef unsigned short u16;
typedef __attribute__((ext_vector_type(8))) short bf16x8;
typedef __attribute__((ext_vector_type(4))) float f32x4;

typedef const __attribute__((address_space(1))) unsigned int* gu32p;
typedef __attribute__((address_space(3))) unsigned int* lu32p;

__device__ __forceinline__ void gl_lds16(const u16* g, u16* l) {
  // async global->LDS DMA, 16B per lane, LDS dest = wave-uniform base + lane*16
  __builtin_amdgcn_global_load_lds((gu32p)(const void*)g, (lu32p)(void*)l, 16, 0, 0);
}

__device__ __forceinline__ u16 f2bf(float f) {
  union { float f; unsigned u; } v; v.f = f;
  unsigned r = v.u + 0x7fffu + ((v.u >> 16) & 1u);
  return (u16)(r >> 16);
}

// ---------------- fp32 -> bf16 convert (x + 4 weights) and RoPE cos/sin table
__global__ void convert_kernel(const float4* __restrict__ x, const float4* __restrict__ wq,
                               const float4* __restrict__ wk, const float4* __restrict__ wv,
                               const float4* __restrict__ wp,
                               u16* __restrict__ xb, u16* __restrict__ wqb, u16* __restrict__ wkb,
                               u16* __restrict__ wvb, u16* __restrict__ wpb,
                               float2* __restrict__ tab) {
  int i = blockIdx.x * 256 + threadIdx.x;
  const int NX = 1048576, NW = 262144, NCONV = NX + 4 * NW;   // 2097152 float4 units
  if (i >= NCONV) {
    int j = i - NCONV;              // 0..65535 : t*32 + d
    int d = j & 31, t = j >> 5;
    float ang = (float)t * expf(-0.28782313662425572f * (float)d);  // ln(10000)/32
    tab[j] = make_float2(cosf(ang), sinf(ang));
    return;
  }
  const float4* src; u16* dst; int off;
  if (i < NX)            { src = x;  dst = xb;  off = i; }
  else if (i < NX + NW)  { src = wq; dst = wqb; off = i - NX; }
  else if (i < NX + 2*NW){ src = wk; dst = wkb; off = i - NX - NW; }
  else if (i < NX + 3*NW){ src = wv; dst = wvb; off = i - NX - 2*NW; }
  else                   { src = wp; dst = wpb; off = i - NX - 3*NW; }
  float4 v = src[off];
  ushort4 ov = make_ushort4(f2bf(v.x), f2bf(v.y), f2bf(v.z), f2bf(v.w));
  *(ushort4*)&dst[off * 4] = ov;
}

// ---------------- NT GEMM: C[M,N] = A[M,K] * B[N,K]^T + bias, K=N=1024, M=4096
// m97 recipe: 128x128 tile, BK=32, unpadded LDS, global_load_lds width=16.
// FUSE_ROPE: apply rotary embedding in epilogue for z<2 (q,k) using tab.
template<int FUSE_ROPE, int OUT_BF16>
__global__ __launch_bounds__(256) void gemm_bt_kernel(
    const u16* __restrict__ A,
    const u16* __restrict__ B0, const u16* __restrict__ B1, const u16* __restrict__ B2,
    const float* __restrict__ bias0, const float* __restrict__ bias1, const float* __restrict__ bias2,
    void* out0, void* out1, void* out2, const float2* __restrict__ tab)
{
  __shared__ __align__(16) u16 As[4096];   // 128 rows x 32, unpadded (DMA layout)
  __shared__ __align__(16) u16 Bs[4096];
  const int z = blockIdx.z;
  const u16* Bw = (z == 0) ? B0 : (z == 1) ? B1 : B2;
  const float* bias = (z == 0) ? bias0 : (z == 1) ? bias1 : bias2;
  void* outv = (z == 0) ? out0 : (z == 1) ? out1 : out2;
  const int tid = threadIdx.x, lane = tid & 63, w = tid >> 6;
  const int wr = w >> 1, wc = w & 1;
  const int quad = lane >> 4, l15 = lane & 15;
  const int m0 = blockIdx.y * 128, n0 = blockIdx.x * 128;
  const int sr = lane >> 2, sc = (lane & 3) * 8;   // staging row-in-16 / col

  f32x4 acc[4][4] = {};
  for (int k0 = 0; k0 < 1024; k0 += 32) {
    __syncthreads();   // all waves done reading previous tile
    #pragma unroll
    for (int p = 0; p < 2; p++) {
      gl_lds16(A  + (m0 + p*64 + w*16 + sr) * 1024 + k0 + sc, As + p*2048 + w*512);
      gl_lds16(Bw + (n0 + p*64 + w*16 + sr) * 1024 + k0 + sc, Bs + p*2048 + w*512);
    }
    __syncthreads();   // vmcnt drain: DMA landed
    bf16x8 af[4], bfr[4];
    #pragma unroll
    for (int mt = 0; mt < 4; mt++)
      af[mt] = *(const bf16x8*)&As[(wr*64 + mt*16 + l15) * 32 + quad*8];
    #pragma unroll
    for (int nt = 0; nt < 4; nt++)
      bfr[nt] = *(const bf16x8*)&Bs[(wc*64 + nt*16 + l15) * 32 + quad*8];
    #pragma unroll
    for (int mt = 0; mt < 4; mt++)
      #pragma unroll
      for (int nt = 0; nt < 4; nt++)
        acc[mt][nt] = __builtin_amdgcn_mfma_f32_16x16x32_bf16(af[mt], bfr[nt], acc[mt][nt], 0, 0, 0);
  }
  // epilogue: bias (+ RoPE for q,k) + store
  #pragma unroll
  for (int mt = 0; mt < 4; mt++) {
    #pragma unroll
    for (int r = 0; r < 4; r++) {
      const int row = m0 + wr*64 + mt*16 + quad*4 + r;
      float v[4];
      #pragma unroll
      for (int nt = 0; nt < 4; nt++)
        v[nt] = acc[mt][nt][r] + bias[n0 + wc*64 + nt*16 + l15];
      if (FUSE_ROPE && z < 2) {
        const int t = row & 2047;
        #pragma unroll
        for (int nt = 0; nt < 2; nt++) {
          const int d = nt*16 + l15;                 // 0..31 within head
          float2 cs = tab[t*32 + d];
          float x0 = v[nt], x1 = v[nt+2];
          v[nt]   = x0 * cs.x - x1 * cs.y;
          v[nt+2] = x1 * cs.x + x0 * cs.y;
        }
      }
      #pragma unroll
      for (int nt = 0; nt < 4; nt++) {
        const int col = n0 + wc*64 + nt*16 + l15;
        if (OUT_BF16) ((u16*)outv)[row * 1024 + col] = f2bf(v[nt]);
        else          ((float*)outv)[row * 1024 + col] = v[nt];
      }
    }
  }
}

// ---------------- causal flash attention
// block x in [0,16): processes q-tiles {x, 31-x} (uniform 33 tile-computes/block),
// sharing K/V LDS tiles between both q-tiles in the overlapping j-range.
// K/V staged via async global_load_lds, double-buffered; V consumed as B-operand
// directly from row-major LDS (no transpose staging).
__global__ __launch_bounds__(256) void attn_kernel(
    const u16* __restrict__ qg, const u16* __restrict__ kg,
    const u16* __restrict__ vg, u16* __restrict__ yg)
{
  __shared__ __align__(16) u16 K_lds[2][64 * 64];
  __shared__ __align__(16) u16 V_lds[2][64 * 64];
  __shared__ __align__(16) u16 P_lds[4][2][16 * 72];   // [wave][slot A/B][16 x 64 +pad]
  const int xb = blockIdx.x;              // 0..15
  const int qa = xb, qbt = 31 - xb;       // qa < qbt always
  const int hh = blockIdx.y, b = blockIdx.z;
  const int tid = threadIdx.x, lane = tid & 63, w = tid >> 6;
  const int quad = lane >> 4, l15 = lane & 15;
  const int bh = b * (2048 * 1024) + hh * 64;

  const int rA = qa*64  + w*16 + l15;
  const int rB = qbt*64 + w*16 + l15;
  bf16x8 qfA0 = *(const bf16x8*)&qg[bh + rA*1024 + quad*8];
  bf16x8 qfA1 = *(const bf16x8*)&qg[bh + rA*1024 + 32 + quad*8];
  bf16x8 qfB0 = *(const bf16x8*)&qg[bh + rB*1024 + quad*8];
  bf16x8 qfB1 = *(const bf16x8*)&qg[bh + rB*1024 + 32 + quad*8];

  f32x4 oA[4] = {}, oB[4] = {};
  float mA[4], lA[4], mB[4], lB[4];
  #pragma unroll
  for (int r = 0; r < 4; r++) { mA[r] = mB[r] = -1e30f; lA[r] = lB[r] = 0.0f; }

  const int srow = lane >> 3, scol = (lane & 7) * 8;
  auto stage = [&](int j, int bf) {
    #pragma unroll
    for (int p = 0; p < 2; p++) {
      const int gidx = bh + (j*64 + p*32 + w*8 + srow) * 1024 + scol;
      gl_lds16(kg + gidx, &K_lds[bf][p*2048 + w*512]);
      gl_lds16(vg + gidx, &V_lds[bf][p*2048 + w*512]);
    }
  };

  const float c = 0.18033688011112042f;   // (1/sqrt(64)) * log2(e)
  auto softmax_p = [&](f32x4* s, float* m, float* l, f32x4* o, int slot, bool diag) {
    if (diag) {
      const int trow = w*16 + quad*4;
      #pragma unroll
      for (int nt = 0; nt < 4; nt++)
        #pragma unroll
        for (int r = 0; r < 4; r++)
          s[nt][r] = (nt*16 + l15 > trow + r) ? -1e30f : s[nt][r] * c;
    } else {
      #pragma unroll
      for (int nt = 0; nt < 4; nt++)
        #pragma unroll
        for (int r = 0; r < 4; r++) s[nt][r] *= c;
    }
    float mx[4];
    #pragma unroll
    for (int r = 0; r < 4; r++)
      mx[r] = fmaxf(fmaxf(s[0][r], s[1][r]), fmaxf(s[2][r], s[3][r]));
    #pragma unroll
    for (int off = 8; off >= 1; off >>= 1)
      #pragma unroll
      for (int r = 0; r < 4; r++) mx[r] = fmaxf(mx[r], __shfl_xor(mx[r], off));
    float al[4];
    #pragma unroll
    for (int r = 0; r < 4; r++) {
      float mn = fmaxf(m[r], mx[r]);
      al[r] = exp2f(m[r] - mn);
      m[r] = mn;
    }
    float rs[4] = {0.f, 0.f, 0.f, 0.f};
    #pragma unroll
    for (int nt = 0; nt < 4; nt++)
      #pragma unroll
      for (int r = 0; r < 4; r++) {
        float pv = exp2f(s[nt][r] - m[r]);
        rs[r] += pv;
        P_lds[w][slot][(quad*4 + r) * 72 + nt*16 + l15] = f2bf(pv);
      }
    #pragma unroll
    for (int off = 8; off >= 1; off >>= 1)
      #pragma unroll
      for (int r = 0; r < 4; r++) rs[r] += __shfl_xor(rs[r], off);
    #pragma unroll
    for (int r = 0; r < 4; r++) l[r] = l[r] * al[r] + rs[r];
    #pragma unroll
    for (int dt = 0; dt < 4; dt++)
      #pragma unroll
      for (int r = 0; r < 4; r++) o[dt][r] *= al[r];
  };

  stage(0, 0);
  for (int j = 0; j <= qbt; j++) {
    __syncthreads();                       // tile j landed; prev reads of other buf done
    if (j < qbt) stage(j + 1, (j + 1) & 1);
    const int bf = j & 1;
    const bool doA = (j <= qa);

    f32x4 sA[4], sB[4];
    #pragma unroll
    for (int nt = 0; nt < 4; nt++) {
      bf16x8 kf0 = *(const bf16x8*)&K_lds[bf][(nt*16 + l15) * 64 + quad*8];
      bf16x8 kf1 = *(const bf16x8*)&K_lds[bf][(nt*16 + l15) * 64 + 32 + quad*8];
      f32x4 z = {};
      z = __builtin_amdgcn_mfma_f32_16x16x32_bf16(qfB0, kf0, z, 0, 0, 0);
      z = __builtin_amdgcn_mfma_f32_16x16x32_bf16(qfB1, kf1, z, 0, 0, 0);
      sB[nt] = z;
      if (doA) {
        f32x4 za = {};
        za = __builtin_amdgcn_mfma_f32_16x16x32_bf16(qfA0, kf0, za, 0, 0, 0);
        za = __builtin_amdgcn_mfma_f32_16x16x32_bf16(qfA1, kf1, za, 0, 0, 0);
        sA[nt] = za;
      }
    }
    softmax_p(sB, mB, lB, oB, 1, j == qbt);
    if (doA) softmax_p(sA, mA, lA, oA, 0, j == qa);

    #pragma unroll
    for (int ss = 0; ss < 2; ss++) {
      bf16x8 pfB = *(const bf16x8*)&P_lds[w][1][l15*72 + ss*32 + quad*8];
      bf16x8 pfA = {};
      if (doA) pfA = *(const bf16x8*)&P_lds[w][0][l15*72 + ss*32 + quad*8];
      #pragma unroll
      for (int dt = 0; dt < 4; dt++) {
        bf16x8 vf;
        #pragma unroll
        for (int jj = 0; jj < 8; jj++)
          vf[jj] = (short)V_lds[bf][(ss*32 + quad*8 + jj) * 64 + dt*16 + l15];
        oB[dt] = __builtin_amdgcn_mfma_f32_16x16x32_bf16(pfB, vf, oB[dt], 0, 0, 0);
        if (doA) oA[dt] = __builtin_amdgcn_mfma_f32_16x16x32_bf16(pfA, vf, oA[dt], 0, 0, 0);
      }
    }
  }

  #pragma unroll
  for (int r = 0; r < 4; r++) {
    float ia = 1.0f / lA[r], ib = 1.0f / lB[r];
    #pragma unroll
    for (int dt = 0; dt < 4; dt++) {
      yg[bh + (qa*64  + w*16 + quad*4 + r) * 1024 + dt*16 + l15] = f2bf(oA[dt][r] * ia);
      yg[bh + (qbt*64 + w*16 + quad*4 + r) * 1024 + dt*16 + l15] = f2bf(oB[dt][r] * ib);
    }
  }
}

extern "C" void kernel_launch(void* const* d_in, const int* in_sizes, int n_in,
                              void* d_out, int out_size, void* d_ws, size_t ws_size,
                              hipStream_t stream) {
  const float* x  = (const float*)d_in[0];
  const float* Wq = (const float*)d_in[1];
  const float* bq = (const float*)d_in[2];
  const float* Wk = (const float*)d_in[3];
  const float* bk = (const float*)d_in[4];
  const float* Wv = (const float*)d_in[5];
  const float* bv = (const float*)d_in[6];
  const float* Wp = (const float*)d_in[7];
  const float* bp = (const float*)d_in[8];

  char* ws = (char*)d_ws;
  u16* xb  = (u16*)(ws);                   // 8 MB, reused as attention output y
  u16* wqb = (u16*)(ws + (8u  << 20));
  u16* wkb = (u16*)(ws + (10u << 20));
  u16* wvb = (u16*)(ws + (12u << 20));
  u16* wpb = (u16*)(ws + (14u << 20));
  u16* qb  = (u16*)(ws + (16u << 20));
  u16* kb  = (u16*)(ws + (24u << 20));
  u16* vb  = (u16*)(ws + (32u << 20));
  float2* tab = (float2*)(ws + (40u << 20));   // 512 KB cos/sin table
  u16* yb = xb;

  convert_kernel<<<8448, 256, 0, stream>>>((const float4*)x, (const float4*)Wq, (const float4*)Wk,
                                           (const float4*)Wv, (const float4*)Wp,
                                           xb, wqb, wkb, wvb, wpb, tab);
  gemm_bt_kernel<1, 1><<<dim3(8, 32, 3), 256, 0, stream>>>(xb, wqb, wkb, wvb, bq, bk, bv,
                                                           (void*)qb, (void*)kb, (void*)vb, tab);
  attn_kernel<<<dim3(16, 16, 2), 256, 0, stream>>>(qb, kb, vb, yb);
  gemm_bt_kernel<0, 0><<<dim3(8, 32, 1), 256, 0, stream>>>(yb, wpb, wpb, wpb, bp, bp, bp,
                                                           (void*)d_out, (void*)d_out, (void*)d_out, tab);
}